// Round 18
// baseline (116.136 us; speedup 1.0000x reference)
//
#include <hip/hip_runtime.h>
#include <hip/hip_bf16.h>
#include <math.h>

#define B_   8
#define S_   4096
#define FIN  256
#define C_   256
#define G_   8
#define D_   32
#define K_   31
#define PAD_ 15
#define FOUT 88

typedef __bf16 bf16;
typedef __attribute__((ext_vector_type(8))) __bf16 bf16x8;
typedef __attribute__((ext_vector_type(4))) __bf16 bf16x4;
typedef __attribute__((ext_vector_type(4))) float f32x4;
typedef __attribute__((ext_vector_type(16))) float f32x16;
typedef __attribute__((ext_vector_type(4))) uint  u32x4;

#define MFMA16(A, B, C) __builtin_amdgcn_mfma_f32_16x16x32_bf16(A, B, C, 0, 0, 0)
#define MFMA32(A, B, C) __builtin_amdgcn_mfma_f32_32x32x16_bf16(A, B, C, 0, 0, 0)

__device__ __forceinline__ bf16 u2b(ushort u) { union { ushort s; bf16 b; } c; c.s = u; return c.b; }
__device__ __forceinline__ ushort b2u(bf16 b) { union { bf16 b; ushort s; } c; c.b = b; return c.s; }

// ---------------- Kernel P: all preps merged (one launch) ------------------
__global__ __launch_bounds__(256) void prep_all(
    const float* __restrict__ Wq, const float* __restrict__ Wk,
    const float* __restrict__ Wv, const float* __restrict__ Wl,
    const float* __restrict__ rel,
    bf16* __restrict__ bth, bf16* __restrict__ btl,
    bf16* __restrict__ wlh, bf16* __restrict__ wll,
    bf16* __restrict__ Vt,
    bf16* __restrict__ relH, bf16* __restrict__ relL)
{
    const int bid = blockIdx.x;
    const int t   = threadIdx.x;

    if (bid < 768) {                       // ---- split_w ----
        const int w = bid >> 8;            // 0..2
        const int k = bid & 255;
        const float* W = (w == 0) ? Wq : (w == 1) ? Wk : Wv;
        const float x = W[(size_t)k * 256 + t];
        const bf16 h = (bf16)x;
        const size_t o = (size_t)w * 65536 + (size_t)t * 256 + k;
        bth[o] = h;
        btl[o] = (bf16)(x - (float)h);
    } else if (bid < 896) {                // ---- split_wl ----
        const int k = (bid - 768) * 2 + (t >> 7);
        const int n = t & 127;
        const float x = (n < FOUT) ? Wl[(size_t)k * FOUT + n] : 0.f;
        const bf16 h = (bf16)x;
        wlh[(size_t)n * 256 + k] = h;
        wll[(size_t)n * 256 + k] = (bf16)(x - (float)h);
    } else if (bid < 1024) {               // ---- vt_pad ----
        const int idx = (bid - 896) * 256 + t;      // 32768
        const int bd  = idx >> 4;
        const int pos = (idx & 15) * 4;
        const int off = (pos < 16) ? pos : 4096 + pos;
        bf16x4 z = {};
        *(bf16x4*)&Vt[(size_t)bd * 4160 + off] = z;
    } else {                               // ---- rel_prep ----
        const int idx = (bid - 1024) * 256 + t;     // 8192
        const int g = idx >> 10, k = (idx >> 5) & 31, d = idx & 31;
        const float v = (k < 31) ? rel[(size_t)(g * 32 + d) * 31 + k] : 0.f;
        const bf16 h = (bf16)v;
        relH[idx] = h;
        relL[idx] = (bf16)(v - (float)h);
    }
}

// ---------------- shared helpers: staged swizzled tiles --------------------
// Swizzle s(r) = ((r>>1)&3) ^ ((r>>3)&3) — period 32 rows, so both 16-row
// (16x16 frag) and 32-row (32x32 frag) read groups are conflict-free.
__device__ __forceinline__ void gload16(const bf16* g, bf16* l) {
    __builtin_amdgcn_global_load_lds(
        (const __attribute__((address_space(1))) void*)g,
        (__attribute__((address_space(3))) void*)l, 16, 0, 0);
}

// bf16 [128 r][32 k] tile; stored chunk (t&3) holds logical chunk (t&3)^s(r).
// row r0 = t>>2 (and r1 = r0+64: both swizzle terms &3-invariant under +64/+8).
__device__ __forceinline__ void stage_tile(const bf16* g, bf16* l, int t) {
    const int lg = ((t & 3) ^ ((t >> 3) & 3) ^ ((t >> 5) & 3)) * 8;
    const int r0 = t >> 2;
    const int r1 = 64 + (t >> 2);
    const int u0 = (t & ~63) * 8;
    gload16(g + (size_t)r0 * 256 + lg, l + u0);
    gload16(g + (size_t)r1 * 256 + lg, l + u0 + 2048);
}

__device__ __forceinline__ bf16x8 frag_ld(const bf16* l, int r, int cl) {
    return *(const bf16x8*)&l[r * 32 + ((cl ^ ((r >> 1) & 3) ^ ((r >> 3) & 3)) << 3)];
}

// ---------------- Kernel 1: QKV projection, 32x32x16 MFMA ------------------
// r17 structure + period-32 swizzle (conflict fix). B-dbuf + counted vmcnt(8).
__global__ __launch_bounds__(256) void qkv_mfma(
    const float* __restrict__ spec,
    const bf16* __restrict__ bth, const bf16* __restrict__ btl,
    bf16* __restrict__ Qh, bf16* __restrict__ Ql,
    uint* __restrict__ Ki,
    bf16* __restrict__ Vt)
{
    __shared__ bf16 lds[6 * 4096];     // Ah | Al | B0h | B0l | B1h | B1l

    const int t   = threadIdx.x;
    const int swz = ((blockIdx.x & 7) * 192) + (blockIdx.x >> 3);   // 1536 % 8 == 0
    const int mt  = swz / 6, nt = swz % 6;
    const int wt  = nt >> 1;           // 0=Q 1=K 2=V
    const int m0  = mt * 128, n0 = (nt & 1) * 128;
    const bool three = (wt < 2);

    const float* a_g = spec + (size_t)m0 * 256;
    const bf16* bh_g = bth + (size_t)wt * 65536 + (size_t)n0 * 256;
    const bf16* bl_g = btl + (size_t)wt * 65536 + (size_t)n0 * 256;

    const int ar  = t >> 1;
    const int ak  = (t & 1) * 16;
    const int as_ = ((ar >> 1) & 3) ^ ((ar >> 3) & 3);
    const int cc0 = ak >> 3;
    bf16* AhW0 = lds +        ar * 32 + (( cc0      ^ as_) << 3);
    bf16* AhW1 = lds +        ar * 32 + (((cc0 + 1) ^ as_) << 3);
    bf16* AlW0 = lds + 4096 + ar * 32 + (( cc0      ^ as_) << 3);
    bf16* AlW1 = lds + 4096 + ar * 32 + (((cc0 + 1) ^ as_) << 3);
    const float* aRow = a_g + (size_t)ar * 256 + ak;

    const int lane = t & 63, wid = t >> 6;
    const int wr = (wid >> 1) * 64, wc = (wid & 1) * 64;
    const int l31 = lane & 31, l5 = lane >> 5;

    f32x16 acc[2][2];
#pragma unroll
    for (int mf = 0; mf < 2; ++mf)
#pragma unroll
        for (int nf = 0; nf < 2; ++nf)
#pragma unroll
            for (int i = 0; i < 16; ++i)
                acc[mf][nf][i] = 0.f;

    stage_tile(bh_g, lds + 8192, t);
    stage_tile(bl_g, lds + 12288, t);
    f32x4 a0 = *(const f32x4*)(aRow);
    f32x4 a1 = *(const f32x4*)(aRow + 4);
    f32x4 a2 = *(const f32x4*)(aRow + 8);
    f32x4 a3 = *(const f32x4*)(aRow + 12);

    for (int ks = 0; ks < 8; ++ks) {
        const int cur = ks & 1;
        bf16* Bcur = lds + 8192 + cur * 8192;

        f32x4 n0_, n1_, n2_, n3_;
        if (ks < 7) {
            bf16* Bnxt = lds + 8192 + (cur ^ 1) * 8192;
            const int ko2 = (ks + 1) * 32;
            stage_tile(bh_g + ko2, Bnxt, t);
            stage_tile(bl_g + ko2, Bnxt + 4096, t);
            n0_ = *(const f32x4*)(aRow + ko2);
            n1_ = *(const f32x4*)(aRow + ko2 + 4);
            n2_ = *(const f32x4*)(aRow + ko2 + 8);
            n3_ = *(const f32x4*)(aRow + ko2 + 12);
        }

        bf16x8 h0, h1, l0, l1;
#pragma unroll
        for (int j = 0; j < 4; ++j) {
            const bf16 x0 = (bf16)a0[j], x1 = (bf16)a1[j];
            const bf16 x2 = (bf16)a2[j], x3 = (bf16)a3[j];
            h0[j] = x0; h0[4 + j] = x1;
            h1[j] = x2; h1[4 + j] = x3;
            l0[j]     = (bf16)(a0[j] - (float)x0);
            l0[4 + j] = (bf16)(a1[j] - (float)x1);
            l1[j]     = (bf16)(a2[j] - (float)x2);
            l1[4 + j] = (bf16)(a3[j] - (float)x3);
        }
        *(bf16x8*)AhW0 = h0;
        *(bf16x8*)AhW1 = h1;
        if (three) {
            *(bf16x8*)AlW0 = l0;
            *(bf16x8*)AlW1 = l1;
        }

        asm volatile("s_waitcnt vmcnt(8) lgkmcnt(0)" ::: "memory");
        __builtin_amdgcn_s_barrier();

        // 32x32 frags: A row = wr + mf*32 + l31, k-chunk = kh*2 + l5
        bf16x8 ah[2][2], bh8[2][2], bl8[2][2];
#pragma unroll
        for (int mf = 0; mf < 2; ++mf)
#pragma unroll
            for (int kh = 0; kh < 2; ++kh)
                ah[mf][kh] = frag_ld(lds, wr + mf * 32 + l31, kh * 2 + l5);
#pragma unroll
        for (int nf = 0; nf < 2; ++nf)
#pragma unroll
            for (int kh = 0; kh < 2; ++kh) {
                bh8[nf][kh] = frag_ld(Bcur,        wc + nf * 32 + l31, kh * 2 + l5);
                bl8[nf][kh] = frag_ld(Bcur + 4096, wc + nf * 32 + l31, kh * 2 + l5);
            }
#pragma unroll
        for (int mf = 0; mf < 2; ++mf)
#pragma unroll
            for (int nf = 0; nf < 2; ++nf)
#pragma unroll
                for (int kh = 0; kh < 2; ++kh) {
                    acc[mf][nf] = MFMA32(ah[mf][kh], bh8[nf][kh], acc[mf][nf]);
                    acc[mf][nf] = MFMA32(ah[mf][kh], bl8[nf][kh], acc[mf][nf]);
                }
        if (three) {
            bf16x8 al[2][2];
#pragma unroll
            for (int mf = 0; mf < 2; ++mf)
#pragma unroll
                for (int kh = 0; kh < 2; ++kh)
                    al[mf][kh] = frag_ld(lds + 4096, wr + mf * 32 + l31, kh * 2 + l5);
#pragma unroll
            for (int mf = 0; mf < 2; ++mf)
#pragma unroll
                for (int nf = 0; nf < 2; ++nf)
#pragma unroll
                    for (int kh = 0; kh < 2; ++kh)
                        acc[mf][nf] = MFMA32(al[mf][kh], bh8[nf][kh], acc[mf][nf]);
        }

        if (ks < 7) {
            __builtin_amdgcn_s_barrier();
            a0 = n0_; a1 = n1_; a2 = n2_; a3 = n3_;
        }
    }

    // C/D layout (32x32): col = lane&31, row = (i&3) + 8*(i>>2) + 4*(lane>>5)
    if (wt == 0) {
#pragma unroll
        for (int mf = 0; mf < 2; ++mf) {
#pragma unroll
            for (int nf = 0; nf < 2; ++nf) {
                const int gc = n0 + wc + nf * 32 + l31;
#pragma unroll
                for (int i = 0; i < 16; ++i) {
                    const int gr = m0 + wr + mf * 32 + (i & 3) + 8 * (i >> 2) + 4 * l5;
                    const float v = acc[mf][nf][i];
                    const bf16 hh = (bf16)v;
                    const size_t off = (size_t)gr * 256 + gc;
                    Qh[off] = hh;
                    Ql[off] = (bf16)(v - (float)hh);
                }
            }
        }
    } else if (wt == 1) {
#pragma unroll
        for (int mf = 0; mf < 2; ++mf) {
#pragma unroll
            for (int nf = 0; nf < 2; ++nf) {
                const int gc = n0 + wc + nf * 32 + l31;
#pragma unroll
                for (int i = 0; i < 16; ++i) {
                    const int gr = m0 + wr + mf * 32 + (i & 3) + 8 * (i >> 2) + 4 * l5;
                    const float v = acc[mf][nf][i];
                    const bf16 hh = (bf16)v;
                    const bf16 ll = (bf16)(v - (float)hh);
                    Ki[(size_t)gr * 256 + gc] =
                        (uint)b2u(hh) | ((uint)b2u(ll) << 16);
                }
            }
        }
    } else {
#pragma unroll
        for (int mf = 0; mf < 2; ++mf) {
#pragma unroll
            for (int nf = 0; nf < 2; ++nf) {
                const int gc = n0 + wc + nf * 32 + l31;
#pragma unroll
                for (int c = 0; c < 4; ++c) {
                    const int gr = m0 + wr + mf * 32 + 8 * c + 4 * l5;   // rows gr..gr+3
                    const int bb = gr >> 12, sr = gr & 4095;
                    bf16x4 pk;
#pragma unroll
                    for (int j = 0; j < 4; ++j) pk[j] = (bf16)acc[mf][nf][4 * c + j];
                    *(bf16x4*)&Vt[(size_t)(bb * 256 + gc) * 4160 + 16 + sr] = pk;
                }
            }
        }
    }
}

// ---------------- Kernel 2: MFMA windowed attention (no-barrier) -----------
// K read from packed Ki (u32 = h | l<<16), unpacked in registers.
__global__ __launch_bounds__(256) void attn_mfma(
    const bf16* __restrict__ Qh, const bf16* __restrict__ Ql,
    const uint* __restrict__ Ki,
    const bf16* __restrict__ Vt,
    const bf16* __restrict__ relH, const bf16* __restrict__ relL,
    float* __restrict__ attn, bf16* __restrict__ Obf)
{
    __shared__ char ldsb[18432];   // 4 waves x (Rbuf/Pf32 2304 | Pbuf 2304)

    const int t    = threadIdx.x;
    const int wid  = t >> 6;
    const int lane = t & 63;
    const int fr   = lane & 15;     // s-col / frag row
    const int q    = lane >> 4;     // k-chunk group
    const int f7   = fr & 7;
    const int sl   = lane >> 2;     // writeback row 0..15
    const int jj   = lane & 3;

    const int bid2 = ((blockIdx.x & 7) << 8) | (blockIdx.x >> 3);   // 2048 % 8 == 0
    const int sg0  = bid2 << 4;
    const int b    = sg0 >> 12;
    const int s0   = sg0 & 4095;

    float* Rbuf = (float*)(ldsb + wid * 4608);          // [32 k][18] f32
    float* Pf32 = Rbuf;                                 // reused: [16 s][36] f32
    bf16*  Pbuf = (bf16*) (ldsb + wid * 4608 + 2304);   // [16 s][72] bf16

    {   // zero Pbuf once (valid band positions rewritten every head)
        uint* p32 = (uint*)Pbuf;
#pragma unroll
        for (int j = 0; j < 9; ++j) p32[lane + 64 * j] = 0u;
    }

    const size_t rowQ = (size_t)(sg0 + fr) * 256;

#pragma unroll
    for (int h = 0; h < 2; ++h) {
        asm volatile("" ::: "memory");
        const int g   = wid * 2 + h;
        const int dof = g * 32 + q * 8;

        const bf16x8 qh8 = *(const bf16x8*)&Qh[rowQ + dof];
        const bf16x8 ql8 = *(const bf16x8*)&Ql[rowQ + dof];

        // ---- QK^T tiles: C[t][s], t0 = s0-16+16*tau ----
        f32x4 e0, e1, e2;
#pragma unroll
        for (int tau = 0; tau < 3; ++tau) {
            const int trel = s0 - 16 + tau * 16 + fr;
            bf16x8 kh8 = {}, kl8 = {};
            if ((unsigned)trel < 4096u) {
                const uint* kp = Ki + ((size_t)(b << 12) + trel) * 256 + dof;
                const u32x4 pA = *(const u32x4*)kp;
                const u32x4 pB = *(const u32x4*)(kp + 4);
#pragma unroll
                for (int j = 0; j < 4; ++j) {
                    const uint ua = pA[j], ub = pB[j];
                    kh8[j]     = u2b((ushort)(ua & 0xffffu));
                    kl8[j]     = u2b((ushort)(ua >> 16));
                    kh8[4 + j] = u2b((ushort)(ub & 0xffffu));
                    kl8[4 + j] = u2b((ushort)(ub >> 16));
                }
            }
            f32x4 a = (f32x4){0.f, 0.f, 0.f, 0.f};
            a = MFMA16(kh8, qh8, a);
            a = MFMA16(kh8, ql8, a);
            a = MFMA16(kl8, qh8, a);
            if (tau == 0) e0 = a; else if (tau == 1) e1 = a; else e2 = a;
        }

        // ---- R[k][s] = rel_g^T . Q_g ; A-frags straight from global ----
#pragma unroll
        for (int kap = 0; kap < 2; ++kap) {
            const size_t ro = (size_t)(g * 32 + kap * 16 + fr) * 32 + q * 8;
            const bf16x8 rh8 = *(const bf16x8*)&relH[ro];
            const bf16x8 rl8 = *(const bf16x8*)&relL[ro];
            f32x4 rc = (f32x4){0.f, 0.f, 0.f, 0.f};
            rc = MFMA16(rh8, qh8, rc);
            rc = MFMA16(rh8, ql8, rc);
            rc = MFMA16(rl8, qh8, rc);
#pragma unroll
            for (int r = 0; r < 4; ++r)
                Rbuf[(kap * 16 + q * 4 + r) * 18 + fr] = rc[r];
        }

        // ---- energies: e + R[t-s+15], band mask, softmax over 31 ----
        float ev[3][4];
        float mx = -3.0e38f;
#pragma unroll
        for (int tau = 0; tau < 3; ++tau) {
#pragma unroll
            for (int r = 0; r < 4; ++r) {
                const int rp = q * 4 + r;
                const int kk = tau * 16 + rp - fr - 1;       // window index
                const float eb = (tau == 0) ? e0[r] : (tau == 1) ? e1[r] : e2[r];
                float v = eb + Rbuf[(kk & 31) * 18 + fr];
                const bool valid = (tau == 1) || ((tau == 0) ? (rp > fr) : (rp < fr));
                v = valid ? v : -3.0e38f;
                ev[tau][r] = v;
                mx = fmaxf(mx, v);
            }
        }
        mx = fmaxf(mx, __shfl_xor(mx, 16));
        mx = fmaxf(mx, __shfl_xor(mx, 32));
        float sum = 0.f;
#pragma unroll
        for (int tau = 0; tau < 3; ++tau)
#pragma unroll
            for (int r = 0; r < 4; ++r) {
                const float p = __expf(ev[tau][r] - mx);
                ev[tau][r] = p;
                sum += p;
            }
        sum += __shfl_xor(sum, 16);
        sum += __shfl_xor(sum, 32);
        const float inv = 1.f / sum;

        // ---- P -> Pf32 (Rbuf reuse) and Pbuf (bf16, chunk-swizzled) ----
#pragma unroll
        for (int tau = 0; tau < 3; ++tau)
#pragma unroll
            for (int r = 0; r < 4; ++r) {
                const int rp = q * 4 + r;
                const int kk = tau * 16 + rp - fr - 1;
                const bool valid = (tau == 1) || ((tau == 0) ? (rp > fr) : (rp < fr));
                if (valid) {
                    const float p = ev[tau][r] * inv;
                    Pf32[fr * 36 + kk] = p;
                    const int tl = tau * 16 + rp;            // t-local in [0,48)
                    Pbuf[fr * 72 + (((tl >> 3) ^ f7) << 3) + (tl & 7)] = (bf16)p;
                }
            }

        // ---- coalesced attn writeback from Pf32 ----
        asm volatile("" ::: "memory");
        {
            float* arow = &attn[((size_t)(sg0 + sl) * 8 + g) * 31];
#pragma unroll
            for (int i = 0; i < 8; ++i) {
                const int k = jj + 4 * i;
                if (k < 31) arow[k] = Pf32[sl * 36 + k];
            }
        }

        // ---- PV swapped: C[d][s] = V[d][t].P[s][t] -> bf16x4 O stores ----
        asm volatile("" ::: "memory");
        const bf16x8 pa0 = *(const bf16x8*)&Pbuf[fr * 72 + ((q ^ f7) << 3)];
        const bf16x8 pa1 = *(const bf16x8*)&Pbuf[fr * 72 + (((4 + q) ^ f7) << 3)];
#pragma unroll
        for (int dl = 0; dl < 2; ++dl) {
            const size_t vrow = (size_t)(b * 256 + g * 32 + dl * 16 + fr) * 4160
                              + s0 + q * 8;
            const bf16x8 v0 = *(const bf16x8*)&Vt[vrow];
            const bf16x8 v1 = *(const bf16x8*)&Vt[vrow + 32];
            f32x4 o = (f32x4){0.f, 0.f, 0.f, 0.f};
            o = MFMA16(v0, pa0, o);
            o = MFMA16(v1, pa1, o);
            bf16x4 pk;
#pragma unroll
            for (int r = 0; r < 4; ++r) pk[r] = (bf16)o[r];
            *(bf16x4*)&Obf[(size_t)(sg0 + fr) * 256 + g * 32 + dl * 16 + (q << 2)] = pk;
        }
    }
}

// ---------------- Kernel 3: frame = sigmoid(O @ WlT + b), MFMA (LDS) -------
__global__ __launch_bounds__(256) void frame_mfma(
    const bf16* __restrict__ O,
    const bf16* __restrict__ wlh, const bf16* __restrict__ wll,
    const float* __restrict__ bl, float* __restrict__ frame)
{
    __shared__ bf16 lds[3 * 4096];     // Ah | Bh | Bl

    const int t  = threadIdx.x;
    const int m0 = blockIdx.x * 128;

    const bf16* a_g = O + (size_t)m0 * 256;

    const int lane = t & 63, wid = t >> 6;
    const int wr = (wid >> 1) * 64, wc = (wid & 1) * 64;
    const int fr = lane & 15, cl = lane >> 4;

    f32x4 acc[4][4];
#pragma unroll
    for (int m = 0; m < 4; ++m)
#pragma unroll
        for (int n = 0; n < 4; ++n)
            acc[m][n] = (f32x4){0.f, 0.f, 0.f, 0.f};

    for (int ks = 0; ks < 8; ++ks) {
        const int ko = ks * 32;
        stage_tile(a_g + ko, lds, t);
        stage_tile(wlh + ko, lds + 4096, t);
        stage_tile(wll + ko, lds + 8192, t);
        __syncthreads();

        bf16x8 ah[4], bh8[4], bl4[4];
#pragma unroll
        for (int m = 0; m < 4; ++m) ah[m] = frag_ld(lds, wr + m * 16 + fr, cl);
#pragma unroll
        for (int n = 0; n < 4; ++n) {
            bh8[n] = frag_ld(lds + 4096, wc + n * 16 + fr, cl);
            bl4[n] = frag_ld(lds + 8192, wc + n * 16 + fr, cl);
        }
#pragma unroll
        for (int m = 0; m < 4; ++m)
#pragma unroll
            for (int n = 0; n < 4; ++n) {
                acc[m][n] = MFMA16(ah[m], bh8[n], acc[m][n]);
                acc[m][n] = MFMA16(ah[m], bl4[n], acc[m][n]);
            }
        __syncthreads();
    }

#pragma unroll
    for (int m = 0; m < 4; ++m) {
        const int gr = m0 + wr + m * 16 + cl * 4;
#pragma unroll
        for (int n = 0; n < 4; ++n) {
            const int gc = wc + n * 16 + fr;
            if (gc < FOUT) {
                const float bb = bl[gc];
#pragma unroll
                for (int i = 0; i < 4; ++i) {
                    const float x = acc[m][n][i] + bb;
                    frame[(size_t)(gr + i) * FOUT + gc] = 1.f / (1.f + __expf(-x));
                }
            }
        }
    }
}

extern "C" void kernel_launch(void* const* d_in, const int* in_sizes, int n_in,
                              void* d_out, int out_size, void* d_ws, size_t ws_size,
                              hipStream_t stream) {
    (void)in_sizes; (void)n_in; (void)out_size; (void)ws_size;
    const float* spec = (const float*)d_in[0];
    const float* Wq   = (const float*)d_in[1];
    const float* Wk   = (const float*)d_in[2];
    const float* Wv   = (const float*)d_in[3];
    const float* rel  = (const float*)d_in[4];
    const float* Wl   = (const float*)d_in[5];
    const float* bl   = (const float*)d_in[6];

    float* frame = (float*)d_out;                              // [B,S,88]
    float* attn  = frame + (size_t)B_ * S_ * FOUT;             // [B,S,G,K]

    // d_out scratch: bth/btl @33.55M ⊂ attn region (prep writes, qkv reads,
    // attn overwrites).
    bf16* bth  = (bf16*)((char*)d_out + 33554432);
    bf16* btl  = bth + 3 * 65536;

    // d_ws: Qh | Ql | Ki(u32 packed) | Vt | Wl hi/lo | rel hi/lo
    // (O bf16 aliases Qh, row-exact, same-wave)
    bf16* Qh   = (bf16*)d_ws;
    bf16* Ql   = Qh + (size_t)8388608;
    uint* Ki   = (uint*)((char*)d_ws + 33554432);   // [32768][256] u32 (h|l<<16)
    bf16* Vt   = (bf16*)((char*)d_ws + 67108864);   // [8][256][4160] bf16
    bf16* wlh  = Vt + (size_t)8 * 256 * 4160;       // [128][256]
    bf16* wll  = wlh + 128 * 256;
    bf16* relH = wll + 128 * 256;                   // [8][32][32]
    bf16* relL = relH + 8192;

    prep_all  <<<dim3(1056), 256, 0, stream>>>(Wq, Wk, Wv, Wl, rel,
                                               bth, btl, wlh, wll, Vt, relH, relL);
    qkv_mfma  <<<dim3(1536), 256, 0, stream>>>(spec, bth, btl, Qh, Ql, Ki, Vt);
    attn_mfma <<<dim3(2048), 256, 0, stream>>>(Qh, Ql, Ki, Vt, relH, relL, attn, Qh);
    frame_mfma<<<dim3(256),  256, 0, stream>>>(Qh, wlh, wll, bl, frame);
}

// Round 19
// 109.228 us; speedup vs baseline: 1.0633x; 1.0633x over previous
//
#include <hip/hip_runtime.h>
#include <hip/hip_bf16.h>
#include <math.h>

#define B_   8
#define S_   4096
#define FIN  256
#define C_   256
#define G_   8
#define D_   32
#define K_   31
#define PAD_ 15
#define FOUT 88

typedef __bf16 bf16;
typedef __attribute__((ext_vector_type(8))) __bf16 bf16x8;
typedef __attribute__((ext_vector_type(4))) __bf16 bf16x4;
typedef __attribute__((ext_vector_type(4))) float f32x4;
typedef __attribute__((ext_vector_type(4))) uint  u32x4;

#define MFMA16(A, B, C) __builtin_amdgcn_mfma_f32_16x16x32_bf16(A, B, C, 0, 0, 0)

__device__ __forceinline__ bf16 u2b(ushort u) { union { ushort s; bf16 b; } c; c.s = u; return c.b; }
__device__ __forceinline__ ushort b2u(bf16 b) { union { bf16 b; ushort s; } c; c.b = b; return c.s; }

// ---------------- Kernel P: all preps merged (one launch) ------------------
__global__ __launch_bounds__(256) void prep_all(
    const float* __restrict__ Wq, const float* __restrict__ Wk,
    const float* __restrict__ Wv, const float* __restrict__ Wl,
    const float* __restrict__ rel,
    bf16* __restrict__ bth, bf16* __restrict__ btl,
    bf16* __restrict__ wlh, bf16* __restrict__ wll,
    bf16* __restrict__ Vt,
    bf16* __restrict__ relH, bf16* __restrict__ relL)
{
    const int bid = blockIdx.x;
    const int t   = threadIdx.x;

    if (bid < 768) {                       // ---- split_w ----
        const int w = bid >> 8;            // 0..2
        const int k = bid & 255;
        const float* W = (w == 0) ? Wq : (w == 1) ? Wk : Wv;
        const float x = W[(size_t)k * 256 + t];
        const bf16 h = (bf16)x;
        const size_t o = (size_t)w * 65536 + (size_t)t * 256 + k;
        bth[o] = h;
        btl[o] = (bf16)(x - (float)h);
    } else if (bid < 896) {                // ---- split_wl ----
        const int k = (bid - 768) * 2 + (t >> 7);
        const int n = t & 127;
        const float x = (n < FOUT) ? Wl[(size_t)k * FOUT + n] : 0.f;
        const bf16 h = (bf16)x;
        wlh[(size_t)n * 256 + k] = h;
        wll[(size_t)n * 256 + k] = (bf16)(x - (float)h);
    } else if (bid < 1024) {               // ---- vt_pad ----
        const int idx = (bid - 896) * 256 + t;      // 32768
        const int bd  = idx >> 4;
        const int pos = (idx & 15) * 4;
        const int off = (pos < 16) ? pos : 4096 + pos;
        bf16x4 z = {};
        *(bf16x4*)&Vt[(size_t)bd * 4160 + off] = z;
    } else {                               // ---- rel_prep ----
        const int idx = (bid - 1024) * 256 + t;     // 8192
        const int g = idx >> 10, k = (idx >> 5) & 31, d = idx & 31;
        const float v = (k < 31) ? rel[(size_t)(g * 32 + d) * 31 + k] : 0.f;
        const bf16 h = (bf16)v;
        relH[idx] = h;
        relL[idx] = (bf16)(v - (float)h);
    }
}

// ---------------- shared helpers: staged swizzled tiles --------------------
// r16 period-8 swizzle (proven 0-conflict for 16x16 frag reads).
__device__ __forceinline__ void gload16(const bf16* g, bf16* l) {
    __builtin_amdgcn_global_load_lds(
        (const __attribute__((address_space(1))) void*)g,
        (__attribute__((address_space(3))) void*)l, 16, 0, 0);
}

// bf16 [128 r][32 k] tile, 16B-chunk swizzle: stored = logical ^ ((r>>1)&3)
__device__ __forceinline__ void stage_tile(const bf16* g, bf16* l, int t) {
    const int lg = ((t & 3) ^ ((t >> 3) & 3)) * 8;
    const int r0 = t >> 2;
    const int r1 = 64 + (t >> 2);
    const int u0 = (t & ~63) * 8;
    gload16(g + (size_t)r0 * 256 + lg, l + u0);
    gload16(g + (size_t)r1 * 256 + lg, l + u0 + 2048);
}

__device__ __forceinline__ bf16x8 frag_ld(const bf16* l, int r, int cl) {
    return *(const bf16x8*)&l[r * 32 + ((cl ^ ((r >> 1) & 3)) << 3)];
}

// ---------------- Kernel 1: QKV projection, B-dbuf + 2-deep A prefetch ----
// r16 schedule with the A-register pipeline extended to depth 2: step ks
// issues B(ks+1) DMA + A(ks+2) loads; cvt consumes A(ks) (arrived 2 steps
// ago). Counted waits keep the 12 newest VMEM ops in flight across the raw
// barrier. K epilogue: packed (h|l<<16) u32 stores. Q,K: 3-term; V: 2-term.
__global__ __launch_bounds__(256) void qkv_mfma(
    const float* __restrict__ spec,
    const bf16* __restrict__ bth, const bf16* __restrict__ btl,
    bf16* __restrict__ Qh, bf16* __restrict__ Ql,
    uint* __restrict__ Ki,
    bf16* __restrict__ Vt)
{
    __shared__ bf16 lds[6 * 4096];     // Ah | Al | B0h | B0l | B1h | B1l

    const int t   = threadIdx.x;
    const int swz = ((blockIdx.x & 7) * 192) + (blockIdx.x >> 3);   // 1536 % 8 == 0
    const int mt  = swz / 6, nt = swz % 6;
    const int wt  = nt >> 1;           // 0=Q 1=K 2=V
    const int m0  = mt * 128, n0 = (nt & 1) * 128;
    const bool three = (wt < 2);

    const float* a_g = spec + (size_t)m0 * 256;
    const bf16* bh_g = bth + (size_t)wt * 65536 + (size_t)n0 * 256;
    const bf16* bl_g = btl + (size_t)wt * 65536 + (size_t)n0 * 256;

    const int ar  = t >> 1;
    const int ak  = (t & 1) * 16;
    const int as_ = (ar >> 1) & 3;
    const int cc0 = ak >> 3;
    bf16* AhW0 = lds +        ar * 32 + (( cc0      ^ as_) << 3);
    bf16* AhW1 = lds +        ar * 32 + (((cc0 + 1) ^ as_) << 3);
    bf16* AlW0 = lds + 4096 + ar * 32 + (( cc0      ^ as_) << 3);
    bf16* AlW1 = lds + 4096 + ar * 32 + (((cc0 + 1) ^ as_) << 3);
    const float* aRow = a_g + (size_t)ar * 256 + ak;

    const int lane = t & 63, wid = t >> 6;
    const int wr = (wid >> 1) * 64, wc = (wid & 1) * 64;
    const int fr = lane & 15, cl = lane >> 4;

    f32x4 acc[4][4];
#pragma unroll
    for (int m = 0; m < 4; ++m)
#pragma unroll
        for (int n = 0; n < 4; ++n)
            acc[m][n] = (f32x4){0.f, 0.f, 0.f, 0.f};

    // prologue: B(0) DMA; A(0), A(1) register loads
    stage_tile(bh_g, lds + 8192, t);
    stage_tile(bl_g, lds + 12288, t);
    f32x4 c0 = *(const f32x4*)(aRow);
    f32x4 c1 = *(const f32x4*)(aRow + 4);
    f32x4 c2 = *(const f32x4*)(aRow + 8);
    f32x4 c3 = *(const f32x4*)(aRow + 12);
    f32x4 p0 = *(const f32x4*)(aRow + 32);
    f32x4 p1 = *(const f32x4*)(aRow + 36);
    f32x4 p2 = *(const f32x4*)(aRow + 40);
    f32x4 p3 = *(const f32x4*)(aRow + 44);

#pragma unroll
    for (int ks = 0; ks < 8; ++ks) {
        const int cur = ks & 1;
        bf16* Bcur = lds + 8192 + cur * 8192;

        if (ks < 7) {                      // B(ks+1) DMA into other buffer
            bf16* Bnxt = lds + 8192 + (cur ^ 1) * 8192;
            const int ko2 = (ks + 1) * 32;
            stage_tile(bh_g + ko2, Bnxt, t);
            stage_tile(bl_g + ko2, Bnxt + 4096, t);
        }
        f32x4 q0, q1, q2, q3;              // A(ks+2) loads
        if (ks < 6) {
            const int ko3 = (ks + 2) * 32;
            q0 = *(const f32x4*)(aRow + ko3);
            q1 = *(const f32x4*)(aRow + ko3 + 4);
            q2 = *(const f32x4*)(aRow + ko3 + 8);
            q3 = *(const f32x4*)(aRow + ko3 + 12);
        }

        // cvt A(ks) (arrived 2 steps ago) -> swizzled ds_write
        bf16x8 h0, h1, l0, l1;
#pragma unroll
        for (int j = 0; j < 4; ++j) {
            const bf16 x0 = (bf16)c0[j], x1 = (bf16)c1[j];
            const bf16 x2 = (bf16)c2[j], x3 = (bf16)c3[j];
            h0[j] = x0; h0[4 + j] = x1;
            h1[j] = x2; h1[4 + j] = x3;
            l0[j]     = (bf16)(c0[j] - (float)x0);
            l0[4 + j] = (bf16)(c1[j] - (float)x1);
            l1[j]     = (bf16)(c2[j] - (float)x2);
            l1[4 + j] = (bf16)(c3[j] - (float)x3);
        }
        *(bf16x8*)AhW0 = h0;
        *(bf16x8*)AhW1 = h1;
        if (three) {
            *(bf16x8*)AlW0 = l0;
            *(bf16x8*)AlW1 = l1;
        }

        // publish: drain B(ks); keep newest {B(ks+1), A(ks+2)} in flight
        if (ks < 6)      asm volatile("s_waitcnt vmcnt(12) lgkmcnt(0)" ::: "memory");
        else if (ks < 7) asm volatile("s_waitcnt vmcnt(8) lgkmcnt(0)"  ::: "memory");
        else             asm volatile("s_waitcnt vmcnt(0) lgkmcnt(0)"  ::: "memory");
        __builtin_amdgcn_s_barrier();

        bf16x8 ah[4], bh8[4], bl8[4];
#pragma unroll
        for (int m = 0; m < 4; ++m) ah[m] = frag_ld(lds, wr + m * 16 + fr, cl);
#pragma unroll
        for (int n = 0; n < 4; ++n) {
            bh8[n] = frag_ld(Bcur,        wc + n * 16 + fr, cl);
            bl8[n] = frag_ld(Bcur + 4096, wc + n * 16 + fr, cl);
        }
#pragma unroll
        for (int m = 0; m < 4; ++m)
#pragma unroll
            for (int n = 0; n < 4; ++n) {
                acc[m][n] = MFMA16(ah[m], bh8[n], acc[m][n]);
                acc[m][n] = MFMA16(ah[m], bl8[n], acc[m][n]);
            }
        if (three) {
            bf16x8 al[4];
#pragma unroll
            for (int m = 0; m < 4; ++m) al[m] = frag_ld(lds + 4096, wr + m * 16 + fr, cl);
#pragma unroll
            for (int m = 0; m < 4; ++m)
#pragma unroll
                for (int n = 0; n < 4; ++n)
                    acc[m][n] = MFMA16(al[m], bh8[n], acc[m][n]);
        }

        if (ks < 7) {
            __builtin_amdgcn_s_barrier();  // WAR guard for A tile / B buffer
            c0 = p0; c1 = p1; c2 = p2; c3 = p3;
            p0 = q0; p1 = q1; p2 = q2; p3 = q3;
        }
    }

    // C/D layout: col = lane&15, row = (lane>>4)*4 + reg
    if (wt == 0) {
#pragma unroll
        for (int m = 0; m < 4; ++m) {
            const int gr = m0 + wr + m * 16 + cl * 4;
#pragma unroll
            for (int n = 0; n < 4; ++n) {
                const int gc = n0 + wc + n * 16 + fr;
#pragma unroll
                for (int i = 0; i < 4; ++i) {
                    const float v = acc[m][n][i];
                    const bf16 hh = (bf16)v;
                    const size_t off = (size_t)(gr + i) * 256 + gc;
                    Qh[off] = hh;
                    Ql[off] = (bf16)(v - (float)hh);
                }
            }
        }
    } else if (wt == 1) {
        // K packed: u32 = h | l<<16 (identical values, half the stores)
#pragma unroll
        for (int m = 0; m < 4; ++m) {
            const int gr = m0 + wr + m * 16 + cl * 4;
#pragma unroll
            for (int n = 0; n < 4; ++n) {
                const int gc = n0 + wc + n * 16 + fr;
#pragma unroll
                for (int i = 0; i < 4; ++i) {
                    const float v = acc[m][n][i];
                    const bf16 hh = (bf16)v;
                    const bf16 ll = (bf16)(v - (float)hh);
                    Ki[(size_t)(gr + i) * 256 + gc] =
                        (uint)b2u(hh) | ((uint)b2u(ll) << 16);
                }
            }
        }
    } else {
#pragma unroll
        for (int m = 0; m < 4; ++m) {
            const int gr = m0 + wr + m * 16 + cl * 4;
            const int bb = gr >> 12, sr = gr & 4095;
#pragma unroll
            for (int n = 0; n < 4; ++n) {
                const int gc = n0 + wc + n * 16 + fr;
                bf16x4 pk;
#pragma unroll
                for (int i = 0; i < 4; ++i) pk[i] = (bf16)acc[m][n][i];
                *(bf16x4*)&Vt[(size_t)(bb * 256 + gc) * 4160 + 16 + sr] = pk;
            }
        }
    }
}

// ---------------- Kernel 2: MFMA windowed attention (no-barrier) -----------
// K read from packed Ki (u32 = h | l<<16), unpacked in registers.
__global__ __launch_bounds__(256) void attn_mfma(
    const bf16* __restrict__ Qh, const bf16* __restrict__ Ql,
    const uint* __restrict__ Ki,
    const bf16* __restrict__ Vt,
    const bf16* __restrict__ relH, const bf16* __restrict__ relL,
    float* __restrict__ attn, bf16* __restrict__ Obf)
{
    __shared__ char ldsb[18432];   // 4 waves x (Rbuf/Pf32 2304 | Pbuf 2304)

    const int t    = threadIdx.x;
    const int wid  = t >> 6;
    const int lane = t & 63;
    const int fr   = lane & 15;     // s-col / frag row
    const int q    = lane >> 4;     // k-chunk group
    const int f7   = fr & 7;
    const int sl   = lane >> 2;     // writeback row 0..15
    const int jj   = lane & 3;

    const int bid2 = ((blockIdx.x & 7) << 8) | (blockIdx.x >> 3);   // 2048 % 8 == 0
    const int sg0  = bid2 << 4;
    const int b    = sg0 >> 12;
    const int s0   = sg0 & 4095;

    float* Rbuf = (float*)(ldsb + wid * 4608);          // [32 k][18] f32
    float* Pf32 = Rbuf;                                 // reused: [16 s][36] f32
    bf16*  Pbuf = (bf16*) (ldsb + wid * 4608 + 2304);   // [16 s][72] bf16

    {   // zero Pbuf once (valid band positions rewritten every head)
        uint* p32 = (uint*)Pbuf;
#pragma unroll
        for (int j = 0; j < 9; ++j) p32[lane + 64 * j] = 0u;
    }

    const size_t rowQ = (size_t)(sg0 + fr) * 256;

#pragma unroll
    for (int h = 0; h < 2; ++h) {
        asm volatile("" ::: "memory");
        const int g   = wid * 2 + h;
        const int dof = g * 32 + q * 8;

        const bf16x8 qh8 = *(const bf16x8*)&Qh[rowQ + dof];
        const bf16x8 ql8 = *(const bf16x8*)&Ql[rowQ + dof];

        // ---- QK^T tiles: C[t][s], t0 = s0-16+16*tau ----
        f32x4 e0, e1, e2;
#pragma unroll
        for (int tau = 0; tau < 3; ++tau) {
            const int trel = s0 - 16 + tau * 16 + fr;
            bf16x8 kh8 = {}, kl8 = {};
            if ((unsigned)trel < 4096u) {
                const uint* kp = Ki + ((size_t)(b << 12) + trel) * 256 + dof;
                const u32x4 pA = *(const u32x4*)kp;
                const u32x4 pB = *(const u32x4*)(kp + 4);
#pragma unroll
                for (int j = 0; j < 4; ++j) {
                    const uint ua = pA[j], ub = pB[j];
                    kh8[j]     = u2b((ushort)(ua & 0xffffu));
                    kl8[j]     = u2b((ushort)(ua >> 16));
                    kh8[4 + j] = u2b((ushort)(ub & 0xffffu));
                    kl8[4 + j] = u2b((ushort)(ub >> 16));
                }
            }
            f32x4 a = (f32x4){0.f, 0.f, 0.f, 0.f};
            a = MFMA16(kh8, qh8, a);
            a = MFMA16(kh8, ql8, a);
            a = MFMA16(kl8, qh8, a);
            if (tau == 0) e0 = a; else if (tau == 1) e1 = a; else e2 = a;
        }

        // ---- R[k][s] = rel_g^T . Q_g ; A-frags straight from global ----
#pragma unroll
        for (int kap = 0; kap < 2; ++kap) {
            const size_t ro = (size_t)(g * 32 + kap * 16 + fr) * 32 + q * 8;
            const bf16x8 rh8 = *(const bf16x8*)&relH[ro];
            const bf16x8 rl8 = *(const bf16x8*)&relL[ro];
            f32x4 rc = (f32x4){0.f, 0.f, 0.f, 0.f};
            rc = MFMA16(rh8, qh8, rc);
            rc = MFMA16(rh8, ql8, rc);
            rc = MFMA16(rl8, qh8, rc);
#pragma unroll
            for (int r = 0; r < 4; ++r)
                Rbuf[(kap * 16 + q * 4 + r) * 18 + fr] = rc[r];
        }

        // ---- energies: e + R[t-s+15], band mask, softmax over 31 ----
        float ev[3][4];
        float mx = -3.0e38f;
#pragma unroll
        for (int tau = 0; tau < 3; ++tau) {
#pragma unroll
            for (int r = 0; r < 4; ++r) {
                const int rp = q * 4 + r;
                const int kk = tau * 16 + rp - fr - 1;       // window index
                const float eb = (tau == 0) ? e0[r] : (tau == 1) ? e1[r] : e2[r];
                float v = eb + Rbuf[(kk & 31) * 18 + fr];
                const bool valid = (tau == 1) || ((tau == 0) ? (rp > fr) : (rp < fr));
                v = valid ? v : -3.0e38f;
                ev[tau][r] = v;
                mx = fmaxf(mx, v);
            }
        }
        mx = fmaxf(mx, __shfl_xor(mx, 16));
        mx = fmaxf(mx, __shfl_xor(mx, 32));
        float sum = 0.f;
#pragma unroll
        for (int tau = 0; tau < 3; ++tau)
#pragma unroll
            for (int r = 0; r < 4; ++r) {
                const float p = __expf(ev[tau][r] - mx);
                ev[tau][r] = p;
                sum += p;
            }
        sum += __shfl_xor(sum, 16);
        sum += __shfl_xor(sum, 32);
        const float inv = 1.f / sum;

        // ---- P -> Pf32 (Rbuf reuse) and Pbuf (bf16, chunk-swizzled) ----
#pragma unroll
        for (int tau = 0; tau < 3; ++tau)
#pragma unroll
            for (int r = 0; r < 4; ++r) {
                const int rp = q * 4 + r;
                const int kk = tau * 16 + rp - fr - 1;
                const bool valid = (tau == 1) || ((tau == 0) ? (rp > fr) : (rp < fr));
                if (valid) {
                    const float p = ev[tau][r] * inv;
                    Pf32[fr * 36 + kk] = p;
                    const int tl = tau * 16 + rp;            // t-local in [0,48)
                    Pbuf[fr * 72 + (((tl >> 3) ^ f7) << 3) + (tl & 7)] = (bf16)p;
                }
            }

        // ---- coalesced attn writeback from Pf32 ----
        asm volatile("" ::: "memory");
        {
            float* arow = &attn[((size_t)(sg0 + sl) * 8 + g) * 31];
#pragma unroll
            for (int i = 0; i < 8; ++i) {
                const int k = jj + 4 * i;
                if (k < 31) arow[k] = Pf32[sl * 36 + k];
            }
        }

        // ---- PV swapped: C[d][s] = V[d][t].P[s][t] -> bf16x4 O stores ----
        asm volatile("" ::: "memory");
        const bf16x8 pa0 = *(const bf16x8*)&Pbuf[fr * 72 + ((q ^ f7) << 3)];
        const bf16x8 pa1 = *(const bf16x8*)&Pbuf[fr * 72 + (((4 + q) ^ f7) << 3)];
#pragma unroll
        for (int dl = 0; dl < 2; ++dl) {
            const size_t vrow = (size_t)(b * 256 + g * 32 + dl * 16 + fr) * 4160
                              + s0 + q * 8;
            const bf16x8 v0 = *(const bf16x8*)&Vt[vrow];
            const bf16x8 v1 = *(const bf16x8*)&Vt[vrow + 32];
            f32x4 o = (f32x4){0.f, 0.f, 0.f, 0.f};
            o = MFMA16(v0, pa0, o);
            o = MFMA16(v1, pa1, o);
            bf16x4 pk;
#pragma unroll
            for (int r = 0; r < 4; ++r) pk[r] = (bf16)o[r];
            *(bf16x4*)&Obf[(size_t)(sg0 + fr) * 256 + g * 32 + dl * 16 + (q << 2)] = pk;
        }
    }
}

// ---------------- Kernel 3: frame = sigmoid(O @ WlT + b), MFMA (LDS) -------
__global__ __launch_bounds__(256) void frame_mfma(
    const bf16* __restrict__ O,
    const bf16* __restrict__ wlh, const bf16* __restrict__ wll,
    const float* __restrict__ bl, float* __restrict__ frame)
{
    __shared__ bf16 lds[3 * 4096];     // Ah | Bh | Bl

    const int t  = threadIdx.x;
    const int m0 = blockIdx.x * 128;

    const bf16* a_g = O + (size_t)m0 * 256;

    const int lane = t & 63, wid = t >> 6;
    const int wr = (wid >> 1) * 64, wc = (wid & 1) * 64;
    const int fr = lane & 15, cl = lane >> 4;

    f32x4 acc[4][4];
#pragma unroll
    for (int m = 0; m < 4; ++m)
#pragma unroll
        for (int n = 0; n < 4; ++n)
            acc[m][n] = (f32x4){0.f, 0.f, 0.f, 0.f};

    for (int ks = 0; ks < 8; ++ks) {
        const int ko = ks * 32;
        stage_tile(a_g + ko, lds, t);
        stage_tile(wlh + ko, lds + 4096, t);
        stage_tile(wll + ko, lds + 8192, t);
        __syncthreads();

        bf16x8 ah[4], bh8[4], bl4[4];
#pragma unroll
        for (int m = 0; m < 4; ++m) ah[m] = frag_ld(lds, wr + m * 16 + fr, cl);
#pragma unroll
        for (int n = 0; n < 4; ++n) {
            bh8[n] = frag_ld(lds + 4096, wc + n * 16 + fr, cl);
            bl4[n] = frag_ld(lds + 8192, wc + n * 16 + fr, cl);
        }
#pragma unroll
        for (int m = 0; m < 4; ++m)
#pragma unroll
            for (int n = 0; n < 4; ++n) {
                acc[m][n] = MFMA16(ah[m], bh8[n], acc[m][n]);
                acc[m][n] = MFMA16(ah[m], bl4[n], acc[m][n]);
            }
        __syncthreads();
    }

#pragma unroll
    for (int m = 0; m < 4; ++m) {
        const int gr = m0 + wr + m * 16 + cl * 4;
#pragma unroll
        for (int n = 0; n < 4; ++n) {
            const int gc = wc + n * 16 + fr;
            if (gc < FOUT) {
                const float bb = bl[gc];
#pragma unroll
                for (int i = 0; i < 4; ++i) {
                    const float x = acc[m][n][i] + bb;
                    frame[(size_t)(gr + i) * FOUT + gc] = 1.f / (1.f + __expf(-x));
                }
            }
        }
    }
}

extern "C" void kernel_launch(void* const* d_in, const int* in_sizes, int n_in,
                              void* d_out, int out_size, void* d_ws, size_t ws_size,
                              hipStream_t stream) {
    (void)in_sizes; (void)n_in; (void)out_size; (void)ws_size;
    const float* spec = (const float*)d_in[0];
    const float* Wq   = (const float*)d_in[1];
    const float* Wk   = (const float*)d_in[2];
    const float* Wv   = (const float*)d_in[3];
    const float* rel  = (const float*)d_in[4];
    const float* Wl   = (const float*)d_in[5];
    const float* bl   = (const float*)d_in[6];

    float* frame = (float*)d_out;                              // [B,S,88]
    float* attn  = frame + (size_t)B_ * S_ * FOUT;             // [B,S,G,K]

    // d_out scratch: bth/btl @33.55M ⊂ attn region (prep writes, qkv reads,
    // attn overwrites).
    bf16* bth  = (bf16*)((char*)d_out + 33554432);
    bf16* btl  = bth + 3 * 65536;

    // d_ws: Qh | Ql | Ki(u32 packed) | Vt | Wl hi/lo | rel hi/lo
    // (O bf16 aliases Qh, row-exact, same-wave)
    bf16* Qh   = (bf16*)d_ws;
    bf16* Ql   = Qh + (size_t)8388608;
    uint* Ki   = (uint*)((char*)d_ws + 33554432);   // [32768][256] u32 (h|l<<16)
    bf16* Vt   = (bf16*)((char*)d_ws + 67108864);   // [8][256][4160] bf16
    bf16* wlh  = Vt + (size_t)8 * 256 * 4160;       // [128][256]
    bf16* wll  = wlh + 128 * 256;
    bf16* relH = wll + 128 * 256;                   // [8][32][32]
    bf16* relL = relH + 8192;

    prep_all  <<<dim3(1056), 256, 0, stream>>>(Wq, Wk, Wv, Wl, rel,
                                               bth, btl, wlh, wll, Vt, relH, relL);
    qkv_mfma  <<<dim3(1536), 256, 0, stream>>>(spec, bth, btl, Qh, Ql, Ki, Vt);
    attn_mfma <<<dim3(2048), 256, 0, stream>>>(Qh, Ql, Ki, Vt, relH, relL, attn, Qh);
    frame_mfma<<<dim3(256),  256, 0, stream>>>(Qh, wlh, wll, bl, frame);
}

// Round 20
// 104.716 us; speedup vs baseline: 1.1091x; 1.0431x over previous
//
#include <hip/hip_runtime.h>
#include <hip/hip_bf16.h>
#include <math.h>

#define B_   8
#define S_   4096
#define FIN  256
#define C_   256
#define G_   8
#define D_   32
#define K_   31
#define PAD_ 15
#define FOUT 88

typedef __bf16 bf16;
typedef __attribute__((ext_vector_type(8))) __bf16 bf16x8;
typedef __attribute__((ext_vector_type(4))) __bf16 bf16x4;
typedef __attribute__((ext_vector_type(4))) float f32x4;
typedef __attribute__((ext_vector_type(4))) uint  u32x4;

#define MFMA16(A, B, C) __builtin_amdgcn_mfma_f32_16x16x32_bf16(A, B, C, 0, 0, 0)

__device__ __forceinline__ bf16 u2b(ushort u) { union { ushort s; bf16 b; } c; c.s = u; return c.b; }
__device__ __forceinline__ ushort b2u(bf16 b) { union { bf16 b; ushort s; } c; c.b = b; return c.s; }

// ---------------- Kernel P: all preps merged (one launch) ------------------
__global__ __launch_bounds__(256) void prep_all(
    const float* __restrict__ Wq, const float* __restrict__ Wk,
    const float* __restrict__ Wv, const float* __restrict__ Wl,
    const float* __restrict__ rel,
    bf16* __restrict__ bth, bf16* __restrict__ btl,
    bf16* __restrict__ wlh, bf16* __restrict__ wll,
    bf16* __restrict__ Vt,
    bf16* __restrict__ relH, bf16* __restrict__ relL)
{
    const int bid = blockIdx.x;
    const int t   = threadIdx.x;

    if (bid < 768) {                       // ---- split_w ----
        const int w = bid >> 8;            // 0..2
        const int k = bid & 255;
        const float* W = (w == 0) ? Wq : (w == 1) ? Wk : Wv;
        const float x = W[(size_t)k * 256 + t];
        const bf16 h = (bf16)x;
        const size_t o = (size_t)w * 65536 + (size_t)t * 256 + k;
        bth[o] = h;
        btl[o] = (bf16)(x - (float)h);
    } else if (bid < 896) {                // ---- split_wl ----
        const int k = (bid - 768) * 2 + (t >> 7);
        const int n = t & 127;
        const float x = (n < FOUT) ? Wl[(size_t)k * FOUT + n] : 0.f;
        const bf16 h = (bf16)x;
        wlh[(size_t)n * 256 + k] = h;
        wll[(size_t)n * 256 + k] = (bf16)(x - (float)h);
    } else if (bid < 1024) {               // ---- vt_pad ----
        const int idx = (bid - 896) * 256 + t;      // 32768
        const int bd  = idx >> 4;
        const int pos = (idx & 15) * 4;
        const int off = (pos < 16) ? pos : 4096 + pos;
        bf16x4 z = {};
        *(bf16x4*)&Vt[(size_t)bd * 4160 + off] = z;
    } else {                               // ---- rel_prep ----
        const int idx = (bid - 1024) * 256 + t;     // 8192
        const int g = idx >> 10, k = (idx >> 5) & 31, d = idx & 31;
        const float v = (k < 31) ? rel[(size_t)(g * 32 + d) * 31 + k] : 0.f;
        const bf16 h = (bf16)v;
        relH[idx] = h;
        relL[idx] = (bf16)(v - (float)h);
    }
}

// ---------------- shared helpers: staged swizzled tiles --------------------
__device__ __forceinline__ void gload16(const bf16* g, bf16* l) {
    __builtin_amdgcn_global_load_lds(
        (const __attribute__((address_space(1))) void*)g,
        (__attribute__((address_space(3))) void*)l, 16, 0, 0);
}

// bf16 [128 r][32 k] tile, 16B-chunk swizzle: stored = logical ^ ((r>>1)&3)
__device__ __forceinline__ void stage_tile(const bf16* g, bf16* l, int t) {
    const int lg = ((t & 3) ^ ((t >> 3) & 3)) * 8;
    const int r0 = t >> 2;
    const int r1 = 64 + (t >> 2);
    const int u0 = (t & ~63) * 8;
    gload16(g + (size_t)r0 * 256 + lg, l + u0);
    gload16(g + (size_t)r1 * 256 + lg, l + u0 + 2048);
}

// bf16 [64 r][32 k] tile (half-height: one gload per thread)
__device__ __forceinline__ void stage_tile64(const bf16* g, bf16* l, int t) {
    const int lg = ((t & 3) ^ ((t >> 3) & 3)) * 8;
    const int r0 = t >> 2;
    const int u0 = (t & ~63) * 8;
    gload16(g + (size_t)r0 * 256 + lg, l + u0);
}

__device__ __forceinline__ bf16x8 frag_ld(const bf16* l, int r, int cl) {
    return *(const bf16x8*)&l[r * 32 + ((cl ^ ((r >> 1) & 3)) << 3)];
}

// ---------------- Kernel 1: QKV projection, B-dbuf + counted vmcnt ---------
// Exact r16 (best measured: ~59 us, 0 conflicts). K epilogue packed u32.
__global__ __launch_bounds__(256) void qkv_mfma(
    const float* __restrict__ spec,
    const bf16* __restrict__ bth, const bf16* __restrict__ btl,
    bf16* __restrict__ Qh, bf16* __restrict__ Ql,
    uint* __restrict__ Ki,
    bf16* __restrict__ Vt)
{
    __shared__ bf16 lds[6 * 4096];     // Ah | Al | B0h | B0l | B1h | B1l

    const int t   = threadIdx.x;
    const int swz = ((blockIdx.x & 7) * 192) + (blockIdx.x >> 3);   // 1536 % 8 == 0
    const int mt  = swz / 6, nt = swz % 6;
    const int wt  = nt >> 1;           // 0=Q 1=K 2=V
    const int m0  = mt * 128, n0 = (nt & 1) * 128;
    const bool three = (wt < 2);

    const float* a_g = spec + (size_t)m0 * 256;
    const bf16* bh_g = bth + (size_t)wt * 65536 + (size_t)n0 * 256;
    const bf16* bl_g = btl + (size_t)wt * 65536 + (size_t)n0 * 256;

    const int ar  = t >> 1;
    const int ak  = (t & 1) * 16;
    const int as_ = (ar >> 1) & 3;
    const int cc0 = ak >> 3;
    bf16* AhW0 = lds +        ar * 32 + (( cc0      ^ as_) << 3);
    bf16* AhW1 = lds +        ar * 32 + (((cc0 + 1) ^ as_) << 3);
    bf16* AlW0 = lds + 4096 + ar * 32 + (( cc0      ^ as_) << 3);
    bf16* AlW1 = lds + 4096 + ar * 32 + (((cc0 + 1) ^ as_) << 3);
    const float* aRow = a_g + (size_t)ar * 256 + ak;

    const int lane = t & 63, wid = t >> 6;
    const int wr = (wid >> 1) * 64, wc = (wid & 1) * 64;
    const int fr = lane & 15, cl = lane >> 4;

    f32x4 acc[4][4];
#pragma unroll
    for (int m = 0; m < 4; ++m)
#pragma unroll
        for (int n = 0; n < 4; ++n)
            acc[m][n] = (f32x4){0.f, 0.f, 0.f, 0.f};

    stage_tile(bh_g, lds + 8192, t);
    stage_tile(bl_g, lds + 12288, t);
    f32x4 a0 = *(const f32x4*)(aRow);
    f32x4 a1 = *(const f32x4*)(aRow + 4);
    f32x4 a2 = *(const f32x4*)(aRow + 8);
    f32x4 a3 = *(const f32x4*)(aRow + 12);

    for (int ks = 0; ks < 8; ++ks) {
        const int cur = ks & 1;
        bf16* Bcur = lds + 8192 + cur * 8192;

        f32x4 n0_, n1_, n2_, n3_;
        if (ks < 7) {
            bf16* Bnxt = lds + 8192 + (cur ^ 1) * 8192;
            const int ko2 = (ks + 1) * 32;
            stage_tile(bh_g + ko2, Bnxt, t);
            stage_tile(bl_g + ko2, Bnxt + 4096, t);
            n0_ = *(const f32x4*)(aRow + ko2);
            n1_ = *(const f32x4*)(aRow + ko2 + 4);
            n2_ = *(const f32x4*)(aRow + ko2 + 8);
            n3_ = *(const f32x4*)(aRow + ko2 + 12);
        }

        bf16x8 h0, h1, l0, l1;
#pragma unroll
        for (int j = 0; j < 4; ++j) {
            const bf16 x0 = (bf16)a0[j], x1 = (bf16)a1[j];
            const bf16 x2 = (bf16)a2[j], x3 = (bf16)a3[j];
            h0[j] = x0; h0[4 + j] = x1;
            h1[j] = x2; h1[4 + j] = x3;
            l0[j]     = (bf16)(a0[j] - (float)x0);
            l0[4 + j] = (bf16)(a1[j] - (float)x1);
            l1[j]     = (bf16)(a2[j] - (float)x2);
            l1[4 + j] = (bf16)(a3[j] - (float)x3);
        }
        *(bf16x8*)AhW0 = h0;
        *(bf16x8*)AhW1 = h1;
        if (three) {
            *(bf16x8*)AlW0 = l0;
            *(bf16x8*)AlW1 = l1;
        }

        asm volatile("s_waitcnt vmcnt(8) lgkmcnt(0)" ::: "memory");
        __builtin_amdgcn_s_barrier();

        bf16x8 ah[4], bh8[4], bl8[4];
#pragma unroll
        for (int m = 0; m < 4; ++m) ah[m] = frag_ld(lds, wr + m * 16 + fr, cl);
#pragma unroll
        for (int n = 0; n < 4; ++n) {
            bh8[n] = frag_ld(Bcur,        wc + n * 16 + fr, cl);
            bl8[n] = frag_ld(Bcur + 4096, wc + n * 16 + fr, cl);
        }
#pragma unroll
        for (int m = 0; m < 4; ++m)
#pragma unroll
            for (int n = 0; n < 4; ++n) {
                acc[m][n] = MFMA16(ah[m], bh8[n], acc[m][n]);
                acc[m][n] = MFMA16(ah[m], bl8[n], acc[m][n]);
            }
        if (three) {
            bf16x8 al[4];
#pragma unroll
            for (int m = 0; m < 4; ++m) al[m] = frag_ld(lds + 4096, wr + m * 16 + fr, cl);
#pragma unroll
            for (int m = 0; m < 4; ++m)
#pragma unroll
                for (int n = 0; n < 4; ++n)
                    acc[m][n] = MFMA16(al[m], bh8[n], acc[m][n]);
        }

        if (ks < 7) {
            __builtin_amdgcn_s_barrier();
            a0 = n0_; a1 = n1_; a2 = n2_; a3 = n3_;
        }
    }

    // C/D layout: col = lane&15, row = (lane>>4)*4 + reg
    if (wt == 0) {
#pragma unroll
        for (int m = 0; m < 4; ++m) {
            const int gr = m0 + wr + m * 16 + cl * 4;
#pragma unroll
            for (int n = 0; n < 4; ++n) {
                const int gc = n0 + wc + n * 16 + fr;
#pragma unroll
                for (int i = 0; i < 4; ++i) {
                    const float v = acc[m][n][i];
                    const bf16 hh = (bf16)v;
                    const size_t off = (size_t)(gr + i) * 256 + gc;
                    Qh[off] = hh;
                    Ql[off] = (bf16)(v - (float)hh);
                }
            }
        }
    } else if (wt == 1) {
        // K packed: u32 = h | l<<16 (identical values, half the stores)
#pragma unroll
        for (int m = 0; m < 4; ++m) {
            const int gr = m0 + wr + m * 16 + cl * 4;
#pragma unroll
            for (int n = 0; n < 4; ++n) {
                const int gc = n0 + wc + n * 16 + fr;
#pragma unroll
                for (int i = 0; i < 4; ++i) {
                    const float v = acc[m][n][i];
                    const bf16 hh = (bf16)v;
                    const bf16 ll = (bf16)(v - (float)hh);
                    Ki[(size_t)(gr + i) * 256 + gc] =
                        (uint)b2u(hh) | ((uint)b2u(ll) << 16);
                }
            }
        }
    } else {
#pragma unroll
        for (int m = 0; m < 4; ++m) {
            const int gr = m0 + wr + m * 16 + cl * 4;
            const int bb = gr >> 12, sr = gr & 4095;
#pragma unroll
            for (int n = 0; n < 4; ++n) {
                const int gc = n0 + wc + n * 16 + fr;
                bf16x4 pk;
#pragma unroll
                for (int i = 0; i < 4; ++i) pk[i] = (bf16)acc[m][n][i];
                *(bf16x4*)&Vt[(size_t)(bb * 256 + gc) * 4160 + 16 + sr] = pk;
            }
        }
    }
}

// ---------------- Kernel 2: MFMA windowed attention (no-barrier, r16) ------
__global__ __launch_bounds__(256) void attn_mfma(
    const bf16* __restrict__ Qh, const bf16* __restrict__ Ql,
    const uint* __restrict__ Ki,
    const bf16* __restrict__ Vt,
    const bf16* __restrict__ relH, const bf16* __restrict__ relL,
    float* __restrict__ attn, bf16* __restrict__ Obf)
{
    __shared__ char ldsb[18432];   // 4 waves x (Rbuf/Pf32 2304 | Pbuf 2304)

    const int t    = threadIdx.x;
    const int wid  = t >> 6;
    const int lane = t & 63;
    const int fr   = lane & 15;     // s-col / frag row
    const int q    = lane >> 4;     // k-chunk group
    const int f7   = fr & 7;
    const int sl   = lane >> 2;     // writeback row 0..15
    const int jj   = lane & 3;

    const int bid2 = ((blockIdx.x & 7) << 8) | (blockIdx.x >> 3);   // 2048 % 8 == 0
    const int sg0  = bid2 << 4;
    const int b    = sg0 >> 12;
    const int s0   = sg0 & 4095;

    float* Rbuf = (float*)(ldsb + wid * 4608);          // [32 k][18] f32
    float* Pf32 = Rbuf;                                 // reused: [16 s][36] f32
    bf16*  Pbuf = (bf16*) (ldsb + wid * 4608 + 2304);   // [16 s][72] bf16

    {   // zero Pbuf once (valid band positions rewritten every head)
        uint* p32 = (uint*)Pbuf;
#pragma unroll
        for (int j = 0; j < 9; ++j) p32[lane + 64 * j] = 0u;
    }

    const size_t rowQ = (size_t)(sg0 + fr) * 256;

#pragma unroll
    for (int h = 0; h < 2; ++h) {
        asm volatile("" ::: "memory");
        const int g   = wid * 2 + h;
        const int dof = g * 32 + q * 8;

        const bf16x8 qh8 = *(const bf16x8*)&Qh[rowQ + dof];
        const bf16x8 ql8 = *(const bf16x8*)&Ql[rowQ + dof];

        // ---- QK^T tiles: C[t][s], t0 = s0-16+16*tau ----
        f32x4 e0, e1, e2;
#pragma unroll
        for (int tau = 0; tau < 3; ++tau) {
            const int trel = s0 - 16 + tau * 16 + fr;
            bf16x8 kh8 = {}, kl8 = {};
            if ((unsigned)trel < 4096u) {
                const uint* kp = Ki + ((size_t)(b << 12) + trel) * 256 + dof;
                const u32x4 pA = *(const u32x4*)kp;
                const u32x4 pB = *(const u32x4*)(kp + 4);
#pragma unroll
                for (int j = 0; j < 4; ++j) {
                    const uint ua = pA[j], ub = pB[j];
                    kh8[j]     = u2b((ushort)(ua & 0xffffu));
                    kl8[j]     = u2b((ushort)(ua >> 16));
                    kh8[4 + j] = u2b((ushort)(ub & 0xffffu));
                    kl8[4 + j] = u2b((ushort)(ub >> 16));
                }
            }
            f32x4 a = (f32x4){0.f, 0.f, 0.f, 0.f};
            a = MFMA16(kh8, qh8, a);
            a = MFMA16(kh8, ql8, a);
            a = MFMA16(kl8, qh8, a);
            if (tau == 0) e0 = a; else if (tau == 1) e1 = a; else e2 = a;
        }

        // ---- R[k][s] = rel_g^T . Q_g ; A-frags straight from global ----
#pragma unroll
        for (int kap = 0; kap < 2; ++kap) {
            const size_t ro = (size_t)(g * 32 + kap * 16 + fr) * 32 + q * 8;
            const bf16x8 rh8 = *(const bf16x8*)&relH[ro];
            const bf16x8 rl8 = *(const bf16x8*)&relL[ro];
            f32x4 rc = (f32x4){0.f, 0.f, 0.f, 0.f};
            rc = MFMA16(rh8, qh8, rc);
            rc = MFMA16(rh8, ql8, rc);
            rc = MFMA16(rl8, qh8, rc);
#pragma unroll
            for (int r = 0; r < 4; ++r)
                Rbuf[(kap * 16 + q * 4 + r) * 18 + fr] = rc[r];
        }

        // ---- energies: e + R[t-s+15], band mask, softmax over 31 ----
        float ev[3][4];
        float mx = -3.0e38f;
#pragma unroll
        for (int tau = 0; tau < 3; ++tau) {
#pragma unroll
            for (int r = 0; r < 4; ++r) {
                const int rp = q * 4 + r;
                const int kk = tau * 16 + rp - fr - 1;       // window index
                const float eb = (tau == 0) ? e0[r] : (tau == 1) ? e1[r] : e2[r];
                float v = eb + Rbuf[(kk & 31) * 18 + fr];
                const bool valid = (tau == 1) || ((tau == 0) ? (rp > fr) : (rp < fr));
                v = valid ? v : -3.0e38f;
                ev[tau][r] = v;
                mx = fmaxf(mx, v);
            }
        }
        mx = fmaxf(mx, __shfl_xor(mx, 16));
        mx = fmaxf(mx, __shfl_xor(mx, 32));
        float sum = 0.f;
#pragma unroll
        for (int tau = 0; tau < 3; ++tau)
#pragma unroll
            for (int r = 0; r < 4; ++r) {
                const float p = __expf(ev[tau][r] - mx);
                ev[tau][r] = p;
                sum += p;
            }
        sum += __shfl_xor(sum, 16);
        sum += __shfl_xor(sum, 32);
        const float inv = 1.f / sum;

        // ---- P -> Pf32 (Rbuf reuse) and Pbuf (bf16, chunk-swizzled) ----
#pragma unroll
        for (int tau = 0; tau < 3; ++tau)
#pragma unroll
            for (int r = 0; r < 4; ++r) {
                const int rp = q * 4 + r;
                const int kk = tau * 16 + rp - fr - 1;
                const bool valid = (tau == 1) || ((tau == 0) ? (rp > fr) : (rp < fr));
                if (valid) {
                    const float p = ev[tau][r] * inv;
                    Pf32[fr * 36 + kk] = p;
                    const int tl = tau * 16 + rp;            // t-local in [0,48)
                    Pbuf[fr * 72 + (((tl >> 3) ^ f7) << 3) + (tl & 7)] = (bf16)p;
                }
            }

        // ---- coalesced attn writeback from Pf32 ----
        asm volatile("" ::: "memory");
        {
            float* arow = &attn[((size_t)(sg0 + sl) * 8 + g) * 31];
#pragma unroll
            for (int i = 0; i < 8; ++i) {
                const int k = jj + 4 * i;
                if (k < 31) arow[k] = Pf32[sl * 36 + k];
            }
        }

        // ---- PV swapped: C[d][s] = V[d][t].P[s][t] -> bf16x4 O stores ----
        asm volatile("" ::: "memory");
        const bf16x8 pa0 = *(const bf16x8*)&Pbuf[fr * 72 + ((q ^ f7) << 3)];
        const bf16x8 pa1 = *(const bf16x8*)&Pbuf[fr * 72 + (((4 + q) ^ f7) << 3)];
#pragma unroll
        for (int dl = 0; dl < 2; ++dl) {
            const size_t vrow = (size_t)(b * 256 + g * 32 + dl * 16 + fr) * 4160
                              + s0 + q * 8;
            const bf16x8 v0 = *(const bf16x8*)&Vt[vrow];
            const bf16x8 v1 = *(const bf16x8*)&Vt[vrow + 32];
            f32x4 o = (f32x4){0.f, 0.f, 0.f, 0.f};
            o = MFMA16(v0, pa0, o);
            o = MFMA16(v1, pa1, o);
            bf16x4 pk;
#pragma unroll
            for (int r = 0; r < 4; ++r) pk[r] = (bf16)o[r];
            *(bf16x4*)&Obf[(size_t)(sg0 + fr) * 256 + g * 32 + dl * 16 + (q << 2)] = pk;
        }
    }
}

// ---------------- Kernel 3: frame = sigmoid(O @ WlT + b), 64-row tiles -----
// 512 blocks (2/CU for latency overlap). Each wave: 16 rows x 128 cols
// (8 n-frags). LDS 20KB: A 64x32 | Bh 128x32 | Bl 128x32.
__global__ __launch_bounds__(256) void frame_mfma(
    const bf16* __restrict__ O,
    const bf16* __restrict__ wlh, const bf16* __restrict__ wll,
    const float* __restrict__ bl, float* __restrict__ frame)
{
    __shared__ bf16 lds[2048 + 2 * 4096];   // A(64x32) | Bh | Bl

    const int t  = threadIdx.x;
    const int m0 = blockIdx.x * 64;

    const bf16* a_g = O + (size_t)m0 * 256;

    const int lane = t & 63, wid = t >> 6;
    const int fr = lane & 15, cl = lane >> 4;
    const int wr2 = wid * 16;              // this wave's 16 rows

    f32x4 acc[8];
#pragma unroll
    for (int n = 0; n < 8; ++n)
        acc[n] = (f32x4){0.f, 0.f, 0.f, 0.f};

    for (int ks = 0; ks < 8; ++ks) {
        const int ko = ks * 32;
        stage_tile64(a_g + ko, lds, t);
        stage_tile(wlh + ko, lds + 2048, t);
        stage_tile(wll + ko, lds + 6144, t);
        __syncthreads();

        const bf16x8 ah = frag_ld(lds, wr2 + fr, cl);
#pragma unroll
        for (int n = 0; n < 8; ++n) {
            const bf16x8 bh8 = frag_ld(lds + 2048, n * 16 + fr, cl);
            const bf16x8 bl8 = frag_ld(lds + 6144, n * 16 + fr, cl);
            acc[n] = MFMA16(ah, bh8, acc[n]);
            acc[n] = MFMA16(ah, bl8, acc[n]);
        }
        __syncthreads();
    }

    const int gr0 = m0 + wr2 + cl * 4;
#pragma unroll
    for (int n = 0; n < 8; ++n) {
        const int gc = n * 16 + fr;
        if (gc < FOUT) {
            const float bb = bl[gc];
#pragma unroll
            for (int i = 0; i < 4; ++i) {
                const float x = acc[n][i] + bb;
                frame[(size_t)(gr0 + i) * FOUT + gc] = 1.f / (1.f + __expf(-x));
            }
        }
    }
}

extern "C" void kernel_launch(void* const* d_in, const int* in_sizes, int n_in,
                              void* d_out, int out_size, void* d_ws, size_t ws_size,
                              hipStream_t stream) {
    (void)in_sizes; (void)n_in; (void)out_size; (void)ws_size;
    const float* spec = (const float*)d_in[0];
    const float* Wq   = (const float*)d_in[1];
    const float* Wk   = (const float*)d_in[2];
    const float* Wv   = (const float*)d_in[3];
    const float* rel  = (const float*)d_in[4];
    const float* Wl   = (const float*)d_in[5];
    const float* bl   = (const float*)d_in[6];

    float* frame = (float*)d_out;                              // [B,S,88]
    float* attn  = frame + (size_t)B_ * S_ * FOUT;             // [B,S,G,K]

    // d_out scratch: bth/btl @33.55M ⊂ attn region (prep writes, qkv reads,
    // attn overwrites).
    bf16* bth  = (bf16*)((char*)d_out + 33554432);
    bf16* btl  = bth + 3 * 65536;

    // d_ws: Qh | Ql | Ki(u32 packed) | Vt | Wl hi/lo | rel hi/lo
    // (O bf16 aliases Qh, row-exact, same-wave)
    bf16* Qh   = (bf16*)d_ws;
    bf16* Ql   = Qh + (size_t)8388608;
    uint* Ki   = (uint*)((char*)d_ws + 33554432);   // [32768][256] u32 (h|l<<16)
    bf16* Vt   = (bf16*)((char*)d_ws + 67108864);   // [8][256][4160] bf16
    bf16* wlh  = Vt + (size_t)8 * 256 * 4160;       // [128][256]
    bf16* wll  = wlh + 128 * 256;
    bf16* relH = wll + 128 * 256;                   // [8][32][32]
    bf16* relL = relH + 8192;

    prep_all  <<<dim3(1056), 256, 0, stream>>>(Wq, Wk, Wv, Wl, rel,
                                               bth, btl, wlh, wll, Vt, relH, relL);
    qkv_mfma  <<<dim3(1536), 256, 0, stream>>>(spec, bth, btl, Qh, Ql, Ki, Vt);
    attn_mfma <<<dim3(2048), 256, 0, stream>>>(Qh, Ql, Ki, Vt, relH, relL, attn, Qh);
    frame_mfma<<<dim3(512),  256, 0, stream>>>(Qh, wlh, wll, bl, frame);
}